// Round 3
// baseline (397.876 us; speedup 1.0000x reference)
//
#include <hip/hip_runtime.h>

typedef __attribute__((ext_vector_type(8))) short short8;
typedef __attribute__((ext_vector_type(4))) float f32x4;
typedef __attribute__((ext_vector_type(8))) unsigned short u16x8;

// sizes (fixed by the problem)
#define BOOKS 8
#define NSAMP 1024
#define OUTF  4096
#define KDIM  256
#define OUT2_OFF 33554432ull   // elements in out1 = 1024*8*4096 (fp32 elements)
#define OUT3_OFF 67108864ull

__device__ __forceinline__ unsigned short f2bf(float f) {
  unsigned int u = __float_as_uint(f);
  u += 0x7fffu + ((u >> 16) & 1u);   // round-to-nearest-even
  return (unsigned short)(u >> 16);
}

__device__ __forceinline__ float wave_sum(float v) {
  #pragma unroll
  for (int off = 32; off; off >>= 1) v += __shfl_xor(v, off, 64);
  return v;
}
__device__ __forceinline__ float wave_max(float v) {
  #pragma unroll
  for (int off = 32; off; off >>= 1) v = fmaxf(v, __shfl_xor(v, off, 64));
  return v;
}

// ---- prep: normalize weight rows -> wn bf16 [8][4096][256] (N x K, K contiguous)
__global__ __launch_bounds__(256) void wnorm_kernel(const float* __restrict__ w,
                                                    unsigned short* __restrict__ wn) {
  int row  = blockIdx.x * 4 + (threadIdx.x >> 6);   // 0..32767
  int lane = threadIdx.x & 63;
  float4 v = ((const float4*)(w + (size_t)row * KDIM))[lane];
  float ss = wave_sum(v.x*v.x + v.y*v.y + v.z*v.z + v.w*v.w);
  float inv = 1.f / fmaxf(sqrtf(ss), 1e-12f);
  ushort4 o;
  o.x = f2bf(v.x*inv); o.y = f2bf(v.y*inv); o.z = f2bf(v.z*inv); o.w = f2bf(v.w*inv);
  *(ushort4*)(wn + (size_t)row * KDIM + lane * 4) = o;
}

// ---- prep: mlp transpose+cast -> mlpT[b][w][d], codebooks cast -> cbb[b][d][w]
__global__ __launch_bounds__(256) void prep_small_kernel(const float* __restrict__ mlp,
                                                         const float* __restrict__ cb,
                                                         unsigned short* __restrict__ mlpT,
                                                         unsigned short* __restrict__ cbb) {
  int blk = blockIdx.x;            // b*256 + d
  int b = blk >> 8, d = blk & 255;
  int w = threadIdx.x;
  size_t src = ((size_t)(b * 256 + d)) * 256 + w;
  cbb[src] = f2bf(cb[src]);
  mlpT[((size_t)b * 256 + w) * 256 + d] = f2bf(mlp[src]);
}

// ---- prep: x raw bf16 [b][i][d] and xn bf16 into A rows 0..1023 per book
__global__ __launch_bounds__(256) void xprep_kernel(const float* __restrict__ input,
                                                    unsigned short* __restrict__ Xb,
                                                    unsigned short* __restrict__ An) {
  int id = blockIdx.x * 4 + (threadIdx.x >> 6);   // b*1024 + i
  int b = id >> 10, i = id & 1023;
  int lane = threadIdx.x & 63;
  float4 v = ((const float4*)(input + (size_t)i * 2048 + b * 256))[lane];
  float ss = wave_sum(v.x*v.x + v.y*v.y + v.z*v.z + v.w*v.w);
  float inv = 1.f / fmaxf(sqrtf(ss), 1e-12f);
  ushort4 r;
  r.x = f2bf(v.x); r.y = f2bf(v.y); r.z = f2bf(v.z); r.w = f2bf(v.w);
  *(ushort4*)(Xb + (size_t)id * KDIM + lane * 4) = r;
  ushort4 n;
  n.x = f2bf(v.x*inv); n.y = f2bf(v.y*inv); n.z = f2bf(v.z*inv); n.w = f2bf(v.w*inv);
  *(ushort4*)(An + ((size_t)b * 2048 + i) * KDIM + lane * 4) = n;
}

// ---- softmax over words; write xc bf16 (GEMM2 A input) and fp32 out3 region
__global__ __launch_bounds__(256) void softmax_kernel(const float* __restrict__ logits,
                                                      unsigned short* __restrict__ XCb,
                                                      float* __restrict__ out3) {
  int id = blockIdx.x * 4 + (threadIdx.x >> 6);   // b*1024 + i
  int b = id >> 10, i = id & 1023;
  int lane = threadIdx.x & 63;
  float4 v = ((const float4*)(logits + (size_t)id * 256))[lane];
  float mx = wave_max(fmaxf(fmaxf(v.x, v.y), fmaxf(v.z, v.w)));
  float e0 = __expf(v.x - mx), e1 = __expf(v.y - mx), e2 = __expf(v.z - mx), e3 = __expf(v.w - mx);
  float s = wave_sum(e0 + e1 + e2 + e3);
  float inv = 1.f / s;
  ushort4 p;
  p.x = f2bf(e0*inv); p.y = f2bf(e1*inv); p.z = f2bf(e2*inv); p.w = f2bf(e3*inv);
  *(ushort4*)(XCb + (size_t)id * 256 + lane * 4) = p;
  float4 pf = make_float4(e0*inv, e1*inv, e2*inv, e3*inv);
  *(float4*)(out3 + ((size_t)i * 8 + b) * 256 + lane * 4) = pf;
}

// ---- normalize s rows -> A rows 1024..2047 per book
__global__ __launch_bounds__(256) void snorm_kernel(const float* __restrict__ s,
                                                    unsigned short* __restrict__ An) {
  int id = blockIdx.x * 4 + (threadIdx.x >> 6);   // b*1024 + i
  int b = id >> 10, i = id & 1023;
  int lane = threadIdx.x & 63;
  float4 v = ((const float4*)(s + (size_t)id * 256))[lane];
  float ss = wave_sum(v.x*v.x + v.y*v.y + v.z*v.z + v.w*v.w);
  float inv = 1.f / fmaxf(sqrtf(ss), 1e-12f);
  ushort4 n;
  n.x = f2bf(v.x*inv); n.y = f2bf(v.y*inv); n.z = f2bf(v.z*inv); n.w = f2bf(v.w*inv);
  *(ushort4*)(An + ((size_t)b * 2048 + 1024 + i) * KDIM + lane * 4) = n;
}

// ---- generic per-book MFMA GEMM: C[b] = A[b] (MxK) * B[b]^T (B stored NxK, K contig)
// EPI=0: store fp32 C [b][M][N].
// EPI=1: fused epilogue (clip, *30, -15 at label col) -> fp32 out1/out2 interleaved layout.
template <int EPI>
__global__ __launch_bounds__(256) void gemm_bt_kernel(const unsigned short* __restrict__ A,
                                                      const unsigned short* __restrict__ B,
                                                      float* __restrict__ Cf,
                                                      const int* __restrict__ label,
                                                      int M, int N, int K) {
  __shared__ __align__(16) unsigned short lA[128 * 32];
  __shared__ __align__(16) unsigned short lB[128 * 32];

  const int b  = blockIdx.z;
  const int m0 = blockIdx.y * 128;
  const int n0 = blockIdx.x * 128;
  const int tid  = threadIdx.x;
  const int wid  = tid >> 6;
  const int lane = tid & 63;
  const int wm = wid & 1, wn = wid >> 1;
  const int r16 = lane & 15;
  const int q   = lane >> 4;

  const unsigned short* Ab = A + (size_t)b * M * K;
  const unsigned short* Bb = B + (size_t)b * N * K;

  f32x4 acc[4][4];
  #pragma unroll
  for (int i = 0; i < 4; ++i)
    #pragma unroll
    for (int j = 0; j < 4; ++j) acc[i][j] = (f32x4){0.f, 0.f, 0.f, 0.f};

  for (int k0 = 0; k0 < K; k0 += 32) {
    // stage A,B tiles [128 rows][32 k] bf16: 512 x 16B each, 2 per thread per matrix
    u16x8 ra[2], rb[2];
    #pragma unroll
    for (int c = 0; c < 2; ++c) {
      int idx = c * 256 + tid;
      int row = idx >> 2, ko = (idx & 3) * 8;
      ra[c] = *(const u16x8*)(Ab + (size_t)(m0 + row) * K + k0 + ko);
      rb[c] = *(const u16x8*)(Bb + (size_t)(n0 + row) * K + k0 + ko);
    }
    __syncthreads();   // prev-iter LDS readers done
    #pragma unroll
    for (int c = 0; c < 2; ++c) {
      int idx = c * 256 + tid;
      int row = idx >> 2, ko = (idx & 3) * 8;
      *(u16x8*)(lA + row * 32 + ko) = ra[c];
      *(u16x8*)(lB + row * 32 + ko) = rb[c];
    }
    __syncthreads();

    // fragments: A[m=lane&15][k=q*8+j]; B^T row n=lane&15, k=q*8+j  (guide §3, m89/m92)
    short8 af[4], bfr[4];
    #pragma unroll
    for (int f = 0; f < 4; ++f) {
      af[f]  = *(const short8*)(lA + (wm * 64 + f * 16 + r16) * 32 + q * 8);
      bfr[f] = *(const short8*)(lB + (wn * 64 + f * 16 + r16) * 32 + q * 8);
    }
    #pragma unroll
    for (int i = 0; i < 4; ++i)
      #pragma unroll
      for (int j = 0; j < 4; ++j)
        acc[i][j] = __builtin_amdgcn_mfma_f32_16x16x32_bf16(af[i], bfr[j], acc[i][j], 0, 0, 0);
  }

  if constexpr (EPI == 0) {
    float* Cb = Cf + (size_t)b * M * N;
    #pragma unroll
    for (int i = 0; i < 4; ++i) {
      int row = m0 + wm * 64 + i * 16 + q * 4;    // C/D: col=lane&15, row=q*4+reg (m89)
      #pragma unroll
      for (int j = 0; j < 4; ++j) {
        int col = n0 + wn * 64 + j * 16 + r16;
        #pragma unroll
        for (int r = 0; r < 4; ++r) Cb[(size_t)(row + r) * N + col] = acc[i][j][r];
      }
    }
  } else {
    // fused epilogue, direct fp32 stores to out[(row>>10)?out2:out1][(i,b,col)]
    #pragma unroll
    for (int i = 0; i < 4; ++i) {
      int row0 = m0 + wm * 64 + i * 16 + q * 4;
      #pragma unroll
      for (int r = 0; r < 4; ++r) {
        int row = row0 + r;                 // 0..2047 within book
        int gi  = row & 1023;               // sample index
        int lb  = label[gi];
        size_t base = (size_t)(row >> 10) * OUT2_OFF + ((size_t)gi * 8 + b) * OUTF;
        #pragma unroll
        for (int j = 0; j < 4; ++j) {
          int col = n0 + wn * 64 + j * 16 + r16;
          float v = fminf(fmaxf(acc[i][j][r], -1.f), 1.f) * 30.f;
          if (col == lb) v -= 15.f;
          Cf[base + col] = v;
        }
      }
    }
  }
}

extern "C" void kernel_launch(void* const* d_in, const int* in_sizes, int n_in,
                              void* d_out, int out_size, void* d_ws, size_t ws_size,
                              hipStream_t stream) {
  const float* input  = (const float*)d_in[0];
  const int*   label  = (const int*)d_in[1];
  const float* weight = (const float*)d_in[2];
  const float* mlp    = (const float*)d_in[3];
  const float* cb     = (const float*)d_in[4];
  float* out = (float*)d_out;   // fp32: reference output dtype is float32

  // d_ws: only wn + An (24 MB total)
  unsigned short* wn = (unsigned short*)d_ws;     // 8*4096*256 = 8,388,608 elems (16 MB)
  unsigned short* An = wn + 8388608;              // 8*2048*256 = 4,194,304 elems (8 MB)

  // scratch overlaid on d_out regions that are only written by the FINAL kernel:
  //   out1 region (134 MB fp32): fbuf (fp32 logits, then s) — 8 MB
  //   out2 region (134 MB fp32): Xb (raw x -> xc), mlpT, cbb — 6 MB
  float*          fbuf = out;
  unsigned short* Xb   = (unsigned short*)(out + OUT2_OFF);    // 2,097,152 bf16 elems
  unsigned short* mlpT = Xb + 2097152;                         //   524,288
  unsigned short* cbb  = mlpT + 524288;                        //   524,288
  float*          out3 = out + OUT3_OFF;

  wnorm_kernel<<<dim3(8192), dim3(256), 0, stream>>>(weight, wn);
  prep_small_kernel<<<dim3(2048), dim3(256), 0, stream>>>(mlp, cb, mlpT, cbb);
  xprep_kernel<<<dim3(2048), dim3(256), 0, stream>>>(input, Xb, An);
  // logits[b][i][w] = x . mlp[:, w]
  gemm_bt_kernel<0><<<dim3(2, 8, 8), dim3(256), 0, stream>>>(Xb, mlpT, fbuf, nullptr,
                                                             1024, 256, 256);
  softmax_kernel<<<dim3(2048), dim3(256), 0, stream>>>(fbuf, Xb, out3);
  // s[b][i][d] = sum_w xc[i,w] * cb[d,w]
  gemm_bt_kernel<0><<<dim3(2, 8, 8), dim3(256), 0, stream>>>(Xb, cbb, fbuf, nullptr,
                                                             1024, 256, 256);
  snorm_kernel<<<dim3(2048), dim3(256), 0, stream>>>(fbuf, An);
  // big fused GEMM: [xn; sn] (2048xK) @ wn^T (4096xK) + clip/scale/margin epilogue
  gemm_bt_kernel<1><<<dim3(32, 16, 8), dim3(256), 0, stream>>>(An, wn, out, label,
                                                               2048, 4096, 256);
}